// Round 6
// baseline (68.392 us; speedup 1.0000x reference)
//
#include <hip/hip_runtime.h>
#include <stdint.h>

#define B_SIZE        262144
#define NUM_CLASSES   1000
#define CODE_LEN      512
#define N_ELEMS       (NUM_CLASSES * CODE_LEN)   // 512000 floats
#define PACKED_WORDS  (NUM_CLASSES * 16)         // 16000 uint32 = 62.5 KB
#define CHUNKS        (NUM_CLASSES * 4)          // 4000 uint4 chunks
#define BLOCKS        256
#define THREADS       512                        // 8 waves/block
#define SAMPLES_PER_BLOCK (B_SIZE / BLOCKS)      // 1024 -> 2 per thread

// ws layout (bytes):
//   [0]      u64 tsum   (single fused count|sum atomic word)
//   [32768]  u32 pack-flags[BLOCKS], DENSE (4 B stride, 1 KB total)
//   [65536]  packed codebook, 16000 u32
#define WS_SUM_OFF     0
#define WS_FLAG_OFF    32768
#define WS_PACKED_OFF  65536
#define PUB_MARKER     0x40000000u    // bit30: poison 0xAAAAAAAA has bit30=0
#define POISON         0xAAAAAAAAu

// R1: RMW-spin vs load-spin: no difference -> spin mechanism never the cost.
// R2: __threadfence() (2304 wave-level buffer_wbl2+buffer_inv serializing at
//     the 8 L2s) was the ~30us cost. Handoff is fence-free since R3.
// R3: fence-free handoff works; 4-byte bypass staging latency-bound.
// R4: dwordx4 sc0 sc1 staging, 8-deep: 64.2us total, kernel ~12.5us. BEST.
// R5: batch-poll(4 loads/iter) + 3-RTT atomicAdd tail: REGRESSED (+3.4,
//     partly fill noise). Reverted both mechanisms.
// R6: strict-improvement forms of both ideas:
//     (a) DENSE flags (4B stride): the polling wave covers all 256 flags
//         with ONE dwordx4 bypass load per thread (thread t watches flags
//         4t..4t+3) -> 1 RTT per round at 1/4 of R5's poll traffic.
//     (b) single-atomic tail: 64-bit atomicAdd of (1<<32)+bsum into a
//         poisoned u64; high half counts blocks, low half accumulates
//         (sum <= 2^27 + 0xAAAAAAAA < 2^32: no carry). The block seeing
//         high == POISON+255 is last and already holds the total -> the
//         whole tail is ONE RMW round-trip, no collector, no fences.
__device__ __forceinline__ unsigned int bypass_load(const unsigned int* p) {
    return __hip_atomic_load(p, __ATOMIC_RELAXED, __HIP_MEMORY_SCOPE_AGENT);
}
__device__ __forceinline__ void bypass_store(unsigned int* p, unsigned int v) {
    __hip_atomic_store(p, v, __ATOMIC_RELAXED, __HIP_MEMORY_SCOPE_AGENT);
}

// Deadlock-safe without cooperative launch: 64 KB LDS + 512 thr => 2
// blocks/CU capacity, so total capacity (512) >= grid (256): every WG is
// resident before any flag-wait can block.
__global__ __launch_bounds__(THREADS) void fused_hamming_kernel(
        const int* __restrict__ output,
        const int* __restrict__ target,
        const float* __restrict__ codebook,
        uint32_t* __restrict__ packed,
        unsigned int* __restrict__ pflags,
        unsigned long long* __restrict__ tsum,
        float* __restrict__ out) {
    __shared__ uint4 lds[CHUNKS];               // 64000 B
    __shared__ unsigned int wsum[THREADS / 64]; // 8 waves

    const int tid = threadIdx.x;

    // Prefetch this thread's 4 indices (cached loads, overlap the pack).
    int base = blockIdx.x * SAMPLES_PER_BLOCK + tid;
    int o0 = output[base],           t0 = target[base];
    int o1 = output[base + THREADS], t1 = target[base + THREADS];

    // ---- phase 1: distributed pack, published via bypass stores ----
    // Block b packs rows {b, 256+b, 512+b, 768+b}; guard is wave-uniform
    // (active/inactive boundary at it=3 is block-aligned, b<=231).
    #pragma unroll
    for (int it = 0; it < 4; it++) {
        int e = it * (BLOCKS * THREADS) + blockIdx.x * THREADS + tid;
        if (e < N_ELEMS) {
            float x = codebook[e];
            unsigned long long m = __ballot(x > 0.5f);
            if ((tid & 31) == 0)
                bypass_store(&packed[e >> 5], (uint32_t)(m >> (tid & 32)));
        }
    }
    // syncthreads drains each wave's vmcnt -> all bypass stores are at the
    // coherence point. Then one coherent RMW sets the bit30-marker flag.
    __syncthreads();
    if (tid == 0)
        atomicExch(&pflags[blockIdx.x], PUB_MARKER);

    // ---- phase 2: poll all 256 dense flags, ONE dwordx4 per thread ----
    // One wave polls; thread t watches flags {4t..4t+3} in a single 16B
    // bypass load (load + waitcnt fused in one asm block). Poison-proof:
    // poison 0xAAAAAAAA lacks bit30.
    if (tid < 64) {
        const unsigned int* fp = &pflags[tid << 2];   // 16B aligned
        for (;;) {
            uint4 v;
            asm volatile("global_load_dwordx4 %0, %1, off sc0 sc1\n\t"
                         "s_waitcnt vmcnt(0)"
                         : "=v"(v) : "v"(fp) : "memory");
            if ((v.x & v.y & v.z & v.w) & PUB_MARKER) break;
        }
    }
    __syncthreads();

    // ---- phase 3: stage table -> LDS via 16B bypass loads (bank-swizzled) --
    // Issue all 8 dwordx4 sc0 sc1 loads (8 outstanding per wave), drain once,
    // then write LDS. sched_barrier(0) after the manual waitcnt (rule #18).
    // chunk k of row r stored at lds[4r + ((k + (r>>2)) & 3)]
    {
        uint4 c[8];
        #pragma unroll
        for (int it = 0; it < 8; it++) {
            int g = tid + THREADS * it;
            if (g < CHUNKS) {
                const uint32_t* src = &packed[(size_t)g << 2];  // 16B aligned
                asm volatile("global_load_dwordx4 %0, %1, off sc0 sc1"
                             : "=v"(c[it]) : "v"(src) : "memory");
            }
        }
        asm volatile("s_waitcnt vmcnt(0)" ::: "memory");
        __builtin_amdgcn_sched_barrier(0);
        #pragma unroll
        for (int it = 0; it < 8; it++) {
            int g = tid + THREADS * it;
            if (g < CHUNKS) {
                int r = g >> 2, k = g & 3;
                lds[(r << 2) + ((k + (r >> 2)) & 3)] = c[it];
            }
        }
    }
    __syncthreads();

    // ---- phase 4: 2 samples/thread, all 16 gathers issued before popc ----
    unsigned int sum = 0;
    {
        uint4 ao[4], at[4], bo[4], bt[4];
        int so0 = (o0 >> 2) & 3, st0 = (t0 >> 2) & 3;
        int so1 = (o1 >> 2) & 3, st1 = (t1 >> 2) & 3;
        #pragma unroll
        for (int k = 0; k < 4; k++) ao[k] = lds[(o0 << 2) + ((k + so0) & 3)];
        #pragma unroll
        for (int k = 0; k < 4; k++) at[k] = lds[(t0 << 2) + ((k + st0) & 3)];
        #pragma unroll
        for (int k = 0; k < 4; k++) bo[k] = lds[(o1 << 2) + ((k + so1) & 3)];
        #pragma unroll
        for (int k = 0; k < 4; k++) bt[k] = lds[(t1 << 2) + ((k + st1) & 3)];

        #pragma unroll
        for (int k = 0; k < 4; k++) {
            sum += __popc(ao[k].x ^ at[k].x) + __popc(ao[k].y ^ at[k].y)
                 + __popc(ao[k].z ^ at[k].z) + __popc(ao[k].w ^ at[k].w);
            sum += __popc(bo[k].x ^ bt[k].x) + __popc(bo[k].y ^ bt[k].y)
                 + __popc(bo[k].z ^ bt[k].z) + __popc(bo[k].w ^ bt[k].w);
        }
    }

    // ---- phase 5: wave(64) reduce, block reduce, single-atomic finish ----
    #pragma unroll
    for (int off = 32; off > 0; off >>= 1)
        sum += __shfl_down(sum, off, 64);
    if ((tid & 63) == 0)
        wsum[tid >> 6] = sum;
    __syncthreads();

    if (tid == 0) {
        unsigned int bsum = 0;
        #pragma unroll
        for (int w = 0; w < THREADS / 64; w++) bsum += wsum[w];
        // Fused count|sum: high half counts blocks, low half accumulates.
        // Word starts at poison 0xAAAAAAAA_AAAAAAAA; low half never carries
        // (0xAAAAAAAA + sum(<2^27) < 2^32). Last block (old>>32 ==
        // POISON+255) holds the grand total in old.lo + bsum.
        unsigned long long old =
            atomicAdd(tsum, (1ULL << 32) + (unsigned long long)bsum);
        if ((unsigned int)(old >> 32) == POISON + (BLOCKS - 1)) {
            unsigned int total = (unsigned int)old + bsum - POISON;
            out[0] = (float)((double)total / (double)B_SIZE);
        }
    }
}

extern "C" void kernel_launch(void* const* d_in, const int* in_sizes, int n_in,
                              void* d_out, int out_size, void* d_ws, size_t ws_size,
                              hipStream_t stream) {
    const int*   output   = (const int*)d_in[0];    // [B] int32
    const int*   target   = (const int*)d_in[1];    // [B] int32
    const float* codebook = (const float*)d_in[2];  // [1000, 512] float32 (0/1)
    float* out = (float*)d_out;

    unsigned long long* tsum   = (unsigned long long*)((char*)d_ws + WS_SUM_OFF);
    unsigned int*       pflags = (unsigned int*)((char*)d_ws + WS_FLAG_OFF);
    uint32_t*           packed = (uint32_t*)((char*)d_ws + WS_PACKED_OFF);

    fused_hamming_kernel<<<BLOCKS, THREADS, 0, stream>>>(
        output, target, codebook, packed, pflags, tsum, out);
}

// Round 7
// 67.404 us; speedup vs baseline: 1.0147x; 1.0147x over previous
//
#include <hip/hip_runtime.h>
#include <stdint.h>

#define B_SIZE        262144
#define NUM_CLASSES   1000
#define CODE_LEN      512
#define N_ELEMS       (NUM_CLASSES * CODE_LEN)   // 512000 floats
#define PACKED_WORDS  (NUM_CLASSES * 16)         // 16000 uint32 = 62.5 KB
#define CHUNKS        (NUM_CLASSES * 4)          // 4000 uint4 chunks
#define BLOCKS        256
#define THREADS       512                        // 8 waves/block
#define SAMPLES_PER_BLOCK (B_SIZE / BLOCKS)      // 1024 -> 2 per thread

// ws layout (bytes):
//   [0]      u64 tsum   (single fused count|sum atomic word)
//   [32768]  u32 pack-flags[BLOCKS], PADDED one per 128B line (R4-proven)
//   [65536]  packed codebook, 16000 u32
#define WS_SUM_OFF     0
#define WS_FLAG_OFF    32768
#define WS_PACKED_OFF  65536
#define LINE_STRIDE    32             // u32 elements = 128 B
#define PUB_MARKER     0x40000000u    // bit30: poison 0xAAAAAAAA has bit30=0
#define POISON         0xAAAAAAAAu

// Session ledger:
// R1: RMW-spin vs load-spin: no difference -> spin mechanism never the cost.
// R2: __threadfence() (wave-level buffer_wbl2+buffer_inv serializing at the
//     8 L2s) was the ~30us cost. Handoff is fence-free since R3.
// R3: fence-free handoff works; 4-byte bypass staging latency-bound.
// R4: dwordx4 sc0 sc1 staging, 8-deep: 64.2us total, kernel ~12.5us. BEST.
// R5: "fewer RTTs" poll (4 independent loads/round): REGRESSED.
// R6: dense flags + 1 dwordx4 poll/round: REGRESSED MORE (with the fastest
//     fills of any round). LESSON: barrier cost is governed by POLL-TRAFFIC
//     CONGESTION on the flag lines (publishers' atomicExch queues behind
//     thousands of reads), not by poll RTT count. R4's dependent-chain poll
//     over 256 padded lines is naturally throttled -> keep it verbatim.
// R7: R4 barrier verbatim + single-u64-RMW tail (count|sum fused): replaces
//     exch-publish + block-0 spin-collector (2 serial RTTs + 256-line spin)
//     with ONE fire-and-forget RMW per block to one line. Strictly less
//     traffic on contended lines — the opposite profile of R5/R6's mistakes.
__device__ __forceinline__ unsigned int bypass_load(const unsigned int* p) {
    return __hip_atomic_load(p, __ATOMIC_RELAXED, __HIP_MEMORY_SCOPE_AGENT);
}
__device__ __forceinline__ void bypass_store(unsigned int* p, unsigned int v) {
    __hip_atomic_store(p, v, __ATOMIC_RELAXED, __HIP_MEMORY_SCOPE_AGENT);
}

// Deadlock-safe without cooperative launch: 64 KB LDS + 512 thr => 2
// blocks/CU capacity, so total capacity (512) >= grid (256): every WG is
// resident before any flag-wait can block.
__global__ __launch_bounds__(THREADS) void fused_hamming_kernel(
        const int* __restrict__ output,
        const int* __restrict__ target,
        const float* __restrict__ codebook,
        uint32_t* __restrict__ packed,
        unsigned int* __restrict__ pflags,
        unsigned long long* __restrict__ tsum,
        float* __restrict__ out) {
    __shared__ uint4 lds[CHUNKS];               // 64000 B
    __shared__ unsigned int wsum[THREADS / 64]; // 8 waves

    const int tid = threadIdx.x;

    // Prefetch this thread's 4 indices (cached loads, overlap the pack).
    int base = blockIdx.x * SAMPLES_PER_BLOCK + tid;
    int o0 = output[base],           t0 = target[base];
    int o1 = output[base + THREADS], t1 = target[base + THREADS];

    // ---- phase 1: distributed pack, published via bypass stores ----
    // Block b packs rows {b, 256+b, 512+b, 768+b}; guard is wave-uniform
    // (active/inactive boundary at it=3 is block-aligned, b<=231).
    #pragma unroll
    for (int it = 0; it < 4; it++) {
        int e = it * (BLOCKS * THREADS) + blockIdx.x * THREADS + tid;
        if (e < N_ELEMS) {
            float x = codebook[e];
            unsigned long long m = __ballot(x > 0.5f);
            if ((tid & 31) == 0)
                bypass_store(&packed[e >> 5], (uint32_t)(m >> (tid & 32)));
        }
    }
    // syncthreads drains each wave's vmcnt -> all bypass stores are at the
    // coherence point. Then one coherent RMW sets the bit30-marker flag.
    __syncthreads();
    if (tid == 0)
        atomicExch(&pflags[blockIdx.x * LINE_STRIDE], PUB_MARKER);

    // ---- phase 2: R4-proven poll: dependent chain, 256 padded lines ----
    // One wave polls; thread i watches flags {i, i+64, i+128, i+192} in
    // sequence. The dependent chain self-throttles (1 outstanding 4B load
    // per thread, spread over 256 lines) so publishers' exch ops never queue
    // behind poll-read backlogs. Poison-proof: poison lacks bit30.
    if (tid < 64) {
        #pragma unroll
        for (int j = 0; j < 4; j++) {
            const unsigned int* f = &pflags[(tid + 64 * j) * LINE_STRIDE];
            while (!(bypass_load(f) & PUB_MARKER)) {}
        }
    }
    __syncthreads();

    // ---- phase 3: stage table -> LDS via 16B bypass loads (bank-swizzled) --
    // Issue all 8 dwordx4 sc0 sc1 loads (8 outstanding per wave), drain once,
    // then write LDS. sched_barrier(0) after the manual waitcnt (rule #18).
    // chunk k of row r stored at lds[4r + ((k + (r>>2)) & 3)]
    {
        uint4 c[8];
        #pragma unroll
        for (int it = 0; it < 8; it++) {
            int g = tid + THREADS * it;
            if (g < CHUNKS) {
                const uint32_t* src = &packed[(size_t)g << 2];  // 16B aligned
                asm volatile("global_load_dwordx4 %0, %1, off sc0 sc1"
                             : "=v"(c[it]) : "v"(src) : "memory");
            }
        }
        asm volatile("s_waitcnt vmcnt(0)" ::: "memory");
        __builtin_amdgcn_sched_barrier(0);
        #pragma unroll
        for (int it = 0; it < 8; it++) {
            int g = tid + THREADS * it;
            if (g < CHUNKS) {
                int r = g >> 2, k = g & 3;
                lds[(r << 2) + ((k + (r >> 2)) & 3)] = c[it];
            }
        }
    }
    __syncthreads();

    // ---- phase 4: 2 samples/thread, all 16 gathers issued before popc ----
    unsigned int sum = 0;
    {
        uint4 ao[4], at[4], bo[4], bt[4];
        int so0 = (o0 >> 2) & 3, st0 = (t0 >> 2) & 3;
        int so1 = (o1 >> 2) & 3, st1 = (t1 >> 2) & 3;
        #pragma unroll
        for (int k = 0; k < 4; k++) ao[k] = lds[(o0 << 2) + ((k + so0) & 3)];
        #pragma unroll
        for (int k = 0; k < 4; k++) at[k] = lds[(t0 << 2) + ((k + st0) & 3)];
        #pragma unroll
        for (int k = 0; k < 4; k++) bo[k] = lds[(o1 << 2) + ((k + so1) & 3)];
        #pragma unroll
        for (int k = 0; k < 4; k++) bt[k] = lds[(t1 << 2) + ((k + st1) & 3)];

        #pragma unroll
        for (int k = 0; k < 4; k++) {
            sum += __popc(ao[k].x ^ at[k].x) + __popc(ao[k].y ^ at[k].y)
                 + __popc(ao[k].z ^ at[k].z) + __popc(ao[k].w ^ at[k].w);
            sum += __popc(bo[k].x ^ bt[k].x) + __popc(bo[k].y ^ bt[k].y)
                 + __popc(bo[k].z ^ bt[k].z) + __popc(bo[k].w ^ bt[k].w);
        }
    }

    // ---- phase 5: wave(64) reduce, block reduce, single-RMW finish ----
    #pragma unroll
    for (int off = 32; off > 0; off >>= 1)
        sum += __shfl_down(sum, off, 64);
    if ((tid & 63) == 0)
        wsum[tid >> 6] = sum;
    __syncthreads();

    if (tid == 0) {
        unsigned int bsum = 0;
        #pragma unroll
        for (int w = 0; w < THREADS / 64; w++) bsum += wsum[w];
        // Fused count|sum in one u64: high half counts blocks, low half
        // accumulates. Word starts at poison 0xAAAAAAAA_AAAAAAAA; low half
        // never carries (0xAAAAAAAA + sum(<2^27) < 2^32). The block seeing
        // old.hi == POISON+255 is last and already holds the grand total in
        // old.lo + bsum. One RMW round-trip total; 255 blocks fire-and-forget.
        unsigned long long old =
            atomicAdd(tsum, (1ULL << 32) + (unsigned long long)bsum);
        if ((unsigned int)(old >> 32) == POISON + (BLOCKS - 1)) {
            unsigned int total = (unsigned int)old + bsum - POISON;
            out[0] = (float)((double)total / (double)B_SIZE);
        }
    }
}

extern "C" void kernel_launch(void* const* d_in, const int* in_sizes, int n_in,
                              void* d_out, int out_size, void* d_ws, size_t ws_size,
                              hipStream_t stream) {
    const int*   output   = (const int*)d_in[0];    // [B] int32
    const int*   target   = (const int*)d_in[1];    // [B] int32
    const float* codebook = (const float*)d_in[2];  // [1000, 512] float32 (0/1)
    float* out = (float*)d_out;

    unsigned long long* tsum   = (unsigned long long*)((char*)d_ws + WS_SUM_OFF);
    unsigned int*       pflags = (unsigned int*)((char*)d_ws + WS_FLAG_OFF);
    uint32_t*           packed = (uint32_t*)((char*)d_ws + WS_PACKED_OFF);

    fused_hamming_kernel<<<BLOCKS, THREADS, 0, stream>>>(
        output, target, codebook, packed, pflags, tsum, out);
}

// Round 8
// 64.990 us; speedup vs baseline: 1.0523x; 1.0371x over previous
//
#include <hip/hip_runtime.h>
#include <stdint.h>

#define B_SIZE        262144
#define NUM_CLASSES   1000
#define CODE_LEN      512
#define N_ELEMS       (NUM_CLASSES * CODE_LEN)   // 512000 floats
#define PACKED_WORDS  (NUM_CLASSES * 16)         // 16000 uint32 = 62.5 KB
#define CHUNKS        (NUM_CLASSES * 4)          // 4000 uint4 chunks
#define BLOCKS        256
#define THREADS       512                        // 8 waves/block
#define SAMPLES_PER_BLOCK (B_SIZE / BLOCKS)      // 1024 -> 2 per thread

// ws layout (bytes):
//   [0]      u32 partials[BLOCKS], one per 128B line (stride 32 u32)
//   [32768]  u32 pack-flags[BLOCKS], one per 128B line
//   [65536]  packed codebook, 16000 u32
#define WS_PART_OFF    0
#define WS_FLAG_OFF    32768
#define WS_PACKED_OFF  65536
#define LINE_STRIDE    32             // u32 elements = 128 B
#define PUB_MARKER     0x40000000u    // bit30: poison 0xAAAAAAAA has bit30=0

// Session ledger (final):
// R1: RMW-spin vs load-spin: no difference -> spin mechanism never the cost.
// R2: __threadfence() (wave-level buffer_wbl2+buffer_inv serializing at the
//     8 L2s) was a ~30us cost. Handoff is fence-free since R3.
// R3: fence-free handoff via relaxed agent-scope (sc0 sc1) atomics works;
//     4-byte bypass staging was latency-bound at the coherence point.
// R4: dwordx4 sc0 sc1 staging, 8-deep/wave: 64.2us total, kernel ~12.5us.
//     BEST MEASURED. This file is R4 verbatim.
// R5: "fewer RTTs" poll (4 independent loads/round): regressed (+3.4).
// R6: dense flags + 1 dwordx4 poll/round: regressed more, with the fastest
//     fills of any round. Lesson: barrier cost is governed by poll-traffic
//     congestion on the flag lines (publishers' atomicExch queues behind
//     poll-read backlog), not poll RTT count. The dependent-chain poll over
//     256 padded lines is naturally self-throttled.
// R7: single-u64-RMW tail: >=65us on a machine-perturbed run (one fill took
//     30ms); no post-R4 change ever beat the +-2-3us noise band in either
//     direction -> reverted to R4.
// Structural floor: 40.7us harness re-poison fill (83% HBM peak) + ~10us
// harness reset dispatches + ~12.5us latency-structured kernel.
__device__ __forceinline__ unsigned int bypass_load(const unsigned int* p) {
    return __hip_atomic_load(p, __ATOMIC_RELAXED, __HIP_MEMORY_SCOPE_AGENT);
}
__device__ __forceinline__ void bypass_store(unsigned int* p, unsigned int v) {
    __hip_atomic_store(p, v, __ATOMIC_RELAXED, __HIP_MEMORY_SCOPE_AGENT);
}

// Deadlock-safe without cooperative launch: 64 KB LDS + 512 thr => 2
// blocks/CU capacity, so total capacity (512) >= grid (256): every WG is
// resident before any flag-wait can block.
__global__ __launch_bounds__(THREADS) void fused_hamming_kernel(
        const int* __restrict__ output,
        const int* __restrict__ target,
        const float* __restrict__ codebook,
        uint32_t* __restrict__ packed,
        unsigned int* __restrict__ pflags,
        unsigned int* __restrict__ partials,
        float* __restrict__ out) {
    __shared__ uint4 lds[CHUNKS];               // 64000 B
    __shared__ unsigned int wsum[THREADS / 64]; // 8 waves

    const int tid = threadIdx.x;

    // Prefetch this thread's 4 indices (cached loads, overlap the pack).
    int base = blockIdx.x * SAMPLES_PER_BLOCK + tid;
    int o0 = output[base],           t0 = target[base];
    int o1 = output[base + THREADS], t1 = target[base + THREADS];

    // ---- phase 1: distributed pack, published via bypass stores ----
    // Block b packs rows {b, 256+b, 512+b, 768+b}; guard is wave-uniform
    // (active/inactive boundary at it=3 is block-aligned, b<=231).
    #pragma unroll
    for (int it = 0; it < 4; it++) {
        int e = it * (BLOCKS * THREADS) + blockIdx.x * THREADS + tid;
        if (e < N_ELEMS) {
            float x = codebook[e];
            unsigned long long m = __ballot(x > 0.5f);
            if ((tid & 31) == 0)
                bypass_store(&packed[e >> 5], (uint32_t)(m >> (tid & 32)));
        }
    }
    // syncthreads drains each wave's vmcnt -> all bypass stores are at the
    // coherence point. Then one coherent RMW sets the bit30-marker flag.
    __syncthreads();
    if (tid == 0)
        atomicExch(&pflags[blockIdx.x * LINE_STRIDE], PUB_MARKER);

    // ---- phase 2: wait for all 256 pack slices (load-only spin, no fence) --
    // One wave polls; thread i watches flags {i, i+64, i+128, i+192} in
    // sequence. The dependent chain self-throttles (1 outstanding 4B load
    // per thread, spread over 256 lines) so publishers' exch ops never queue
    // behind poll-read backlog. Poison-proof: poison lacks bit30.
    if (tid < 64) {
        #pragma unroll
        for (int j = 0; j < 4; j++) {
            const unsigned int* f = &pflags[(tid + 64 * j) * LINE_STRIDE];
            while (!(bypass_load(f) & PUB_MARKER)) {}
        }
    }
    __syncthreads();

    // ---- phase 3: stage table -> LDS via 16B bypass loads (bank-swizzled) --
    // Issue all 8 dwordx4 sc0 sc1 loads (8 outstanding per wave), drain once,
    // then write LDS. sched_barrier(0) after the manual waitcnt (rule #18).
    // chunk k of row r stored at lds[4r + ((k + (r>>2)) & 3)]
    {
        uint4 c[8];
        #pragma unroll
        for (int it = 0; it < 8; it++) {
            int g = tid + THREADS * it;
            if (g < CHUNKS) {
                const uint32_t* src = &packed[(size_t)g << 2];  // 16B aligned
                asm volatile("global_load_dwordx4 %0, %1, off sc0 sc1"
                             : "=v"(c[it]) : "v"(src) : "memory");
            }
        }
        asm volatile("s_waitcnt vmcnt(0)" ::: "memory");
        __builtin_amdgcn_sched_barrier(0);
        #pragma unroll
        for (int it = 0; it < 8; it++) {
            int g = tid + THREADS * it;
            if (g < CHUNKS) {
                int r = g >> 2, k = g & 3;
                lds[(r << 2) + ((k + (r >> 2)) & 3)] = c[it];
            }
        }
    }
    __syncthreads();

    // ---- phase 4: 2 samples/thread, all 16 gathers issued before popc ----
    unsigned int sum = 0;
    {
        uint4 ao[4], at[4], bo[4], bt[4];
        int so0 = (o0 >> 2) & 3, st0 = (t0 >> 2) & 3;
        int so1 = (o1 >> 2) & 3, st1 = (t1 >> 2) & 3;
        #pragma unroll
        for (int k = 0; k < 4; k++) ao[k] = lds[(o0 << 2) + ((k + so0) & 3)];
        #pragma unroll
        for (int k = 0; k < 4; k++) at[k] = lds[(t0 << 2) + ((k + st0) & 3)];
        #pragma unroll
        for (int k = 0; k < 4; k++) bo[k] = lds[(o1 << 2) + ((k + so1) & 3)];
        #pragma unroll
        for (int k = 0; k < 4; k++) bt[k] = lds[(t1 << 2) + ((k + st1) & 3)];

        #pragma unroll
        for (int k = 0; k < 4; k++) {
            sum += __popc(ao[k].x ^ at[k].x) + __popc(ao[k].y ^ at[k].y)
                 + __popc(ao[k].z ^ at[k].z) + __popc(ao[k].w ^ at[k].w);
            sum += __popc(bo[k].x ^ bt[k].x) + __popc(bo[k].y ^ bt[k].y)
                 + __popc(bo[k].z ^ bt[k].z) + __popc(bo[k].w ^ bt[k].w);
        }
    }

    // ---- phase 5: wave(64) reduce, block reduce, publish own 128B line ----
    #pragma unroll
    for (int off = 32; off > 0; off >>= 1)
        sum += __shfl_down(sum, off, 64);
    if ((tid & 63) == 0)
        wsum[tid >> 6] = sum;
    __syncthreads();

    if (tid == 0) {
        unsigned int bsum = 0;
        #pragma unroll
        for (int w = 0; w < THREADS / 64; w++) bsum += wsum[w];
        // bsum <= 1024*512 = 2^19, bit30 marker is safe; flag+data share one
        // word -> transfer happens through the atomic itself, fence-free.
        atomicExch(&partials[blockIdx.x * LINE_STRIDE], bsum | PUB_MARKER);
    }

    // ---- collector: block 0 load-spins on 256 distinct lines, writes mean --
    if (blockIdx.x == 0) {
        __syncthreads();    // protect wsum reuse below
        unsigned int v = 0;
        if (tid < BLOCKS) {
            do {
                v = bypass_load(&partials[tid * LINE_STRIDE]);
            } while (!(v & PUB_MARKER));
            v &= ~PUB_MARKER;
        }
        #pragma unroll
        for (int off = 32; off > 0; off >>= 1)
            v += __shfl_down(v, off, 64);
        if ((tid & 63) == 0)
            wsum[tid >> 6] = v;     // waves 4..7 contribute 0
        __syncthreads();
        if (tid == 0) {
            unsigned long long total = 0;
            #pragma unroll
            for (int w = 0; w < THREADS / 64; w++) total += wsum[w];
            out[0] = (float)((double)total / (double)B_SIZE);
        }
    }
}

extern "C" void kernel_launch(void* const* d_in, const int* in_sizes, int n_in,
                              void* d_out, int out_size, void* d_ws, size_t ws_size,
                              hipStream_t stream) {
    const int*   output   = (const int*)d_in[0];    // [B] int32
    const int*   target   = (const int*)d_in[1];    // [B] int32
    const float* codebook = (const float*)d_in[2];  // [1000, 512] float32 (0/1)
    float* out = (float*)d_out;

    unsigned int* partials = (unsigned int*)((char*)d_ws + WS_PART_OFF);
    unsigned int* pflags   = (unsigned int*)((char*)d_ws + WS_FLAG_OFF);
    uint32_t*     packed   = (uint32_t*)((char*)d_ws + WS_PACKED_OFF);

    fused_hamming_kernel<<<BLOCKS, THREADS, 0, stream>>>(
        output, target, codebook, packed, pflags, partials, out);
}